// Round 6
// baseline (650.166 us; speedup 1.0000x reference)
//
#include <hip/hip_runtime.h>
#include <math.h>

#define NB 32
#define NH 480
#define NW 640
#define HW (NH*NW)
#define BHW (NB*HW)
#define CAP 16384
#define TOPK 1024
#define NMS_T 0.3f
#define TX 64
#define TY 16

__device__ __forceinline__ bool analytic_mask(
    float xf, float yf, float h0, float h1, float h2, float h3, float h4,
    float h5, float h6, float h7, float h8)
{
    float w0 = h0 * xf + h1 * yf + h2;
    float w1 = h3 * xf + h4 * yf + h5;
    float wz = h6 * xf + h7 * yf + h8;
    float z = wz + 1e-8f;
    float px = w0 / z, py = w1 / z;
    float x0f = floorf(px), y0f = floorf(py);
    float wx = px - x0f, wy = py - y0f;
    int x0 = (int)x0f, y0 = (int)y0f;
    bool vx0 = (x0 >= 0) && (x0 <= NW - 1);
    bool vx1 = (x0 + 1 >= 0) && (x0 + 1 <= NW - 1);
    bool vy0 = (y0 >= 0) && (y0 <= NH - 1);
    bool vy1 = (y0 + 1 >= 0) && (y0 + 1 <= NH - 1);
    return (vx0 && vy0)
        || (wx > 0.f && vx1 && vy0)
        || (wy > 0.f && vx0 && vy1)
        || (wx > 0.f && wy > 0.f && vx1 && vy1);
}

// ---------------- fused warp + analytic-mask erode + mask multiply + norm ----
__global__ __launch_bounds__(256) void prep_kernel(
    const float* __restrict__ s1, const float* __restrict__ s2,
    const float* __restrict__ homo, float* __restrict__ s1m,
    float* __restrict__ w2m, float* __restrict__ mask_out,
    unsigned int* __restrict__ normbuck)
{
    __shared__ unsigned char msk[(TY + 2) * (TX + 2)];
    __shared__ unsigned int ws[4];
    int tlin = blockIdx.x;          // 0..299
    int b = blockIdx.y;
    int tyi = tlin / (NW / TX);
    int txi = tlin - tyi * (NW / TX);
    int bx0 = txi * TX, by0 = tyi * TY;
    int tid = threadIdx.x;

    const float* h = homo + b * 9;
    float h0 = h[0], h1 = h[1], h2 = h[2], h3 = h[3], h4 = h[4];
    float h5 = h[5], h6 = h[6], h7 = h[7], h8 = h[8];

    for (int i = tid; i < (TY + 2) * (TX + 2); i += 256) {
        int ly = i / (TX + 2), lx = i - ly * (TX + 2);
        int gy = by0 + ly - 1, gx = bx0 + lx - 1;
        int m = 0;
        if (gy >= 0 && gy < NH && gx >= 0 && gx < NW)
            m = analytic_mask((float)gx, (float)gy, h0, h1, h2, h3, h4, h5, h6, h7, h8) ? 1 : 0;
        msk[i] = (unsigned char)m;
    }
    __syncthreads();

    int tx = tid & 63, ty0v = (tid >> 6) * 4;
    const float* img2 = s2 + (size_t)b * HW;
    int cnt = 0;
#pragma unroll
    for (int r = 0; r < 4; ++r) {
        int ty = ty0v + r;
        int gx = bx0 + tx, gy = by0 + ty;
        int em;
        if (gx == 0 || gx == NW - 1 || gy == 0 || gy == NH - 1) {
            em = 0;
        } else {
            const unsigned char* q = &msk[ty * (TX + 2) + tx];
            em = q[0] & q[1] & q[2]
               & q[TX + 2] & q[TX + 3] & q[TX + 4]
               & q[2 * (TX + 2)] & q[2 * (TX + 2) + 1] & q[2 * (TX + 2) + 2];
        }
        float xf = (float)gx, yf = (float)gy;
        float w0 = h0 * xf + h1 * yf + h2;
        float w1 = h3 * xf + h4 * yf + h5;
        float wz = h6 * xf + h7 * yf + h8;
        float z = wz + 1e-8f;
        float px = w0 / z, py = w1 / z;
        float x0f = floorf(px), y0f = floorf(py);
        float wx = px - x0f, wy = py - y0f;
        int x0 = (int)x0f, y0 = (int)y0f;
        bool vx0 = (x0 >= 0) && (x0 <= NW - 1);
        bool vx1 = (x0 + 1 >= 0) && (x0 + 1 <= NW - 1);
        bool vy0 = (y0 >= 0) && (y0 <= NH - 1);
        bool vy1 = (y0 + 1 >= 0) && (y0 + 1 <= NH - 1);
        float v00 = (vx0 && vy0) ? img2[y0 * NW + x0] : 0.f;
        float v01 = (vx1 && vy0) ? img2[y0 * NW + x0 + 1] : 0.f;
        float v10 = (vx0 && vy1) ? img2[(y0 + 1) * NW + x0] : 0.f;
        float v11 = (vx1 && vy1) ? img2[(y0 + 1) * NW + x0 + 1] : 0.f;
        float val = v00 * (1.f - wx) * (1.f - wy)
                  + v01 * wx * (1.f - wy)
                  + v10 * (1.f - wx) * wy
                  + v11 * wx * wy;

        float emf = (float)em;
        int gidx = b * HW + gy * NW + gx;
        mask_out[gidx] = emf;
        s1m[gidx] = s1[gidx] * emf;
        w2m[gidx] = val * emf;
        cnt += em;
    }
    for (int off = 32; off; off >>= 1) cnt += __shfl_down(cnt, off, 64);
    int lane = tid & 63, wv = tid >> 6;
    if (lane == 0) ws[wv] = (unsigned int)cnt;
    __syncthreads();
    if (tid == 0) {
        int bid = blockIdx.y * 300 + blockIdx.x;
        atomicAdd(&normbuck[(bid & 255) * 16], ws[0] + ws[1] + ws[2] + ws[3]);
    }
}

// --------------------------- NMS: LDS-tiled dense 5x5 max, compacted append --
__global__ __launch_bounds__(256) void nms_kernel(
    const float* __restrict__ s1m, const float* __restrict__ w2m,
    unsigned long long* __restrict__ cand, int* __restrict__ cntp)
{
    __shared__ float tile[(TY + 4) * (TX + 4)];
    __shared__ int wsum[4];
    __shared__ int base_sh;
    int tlin = blockIdx.x;
    int b = blockIdx.y;
    int tyi = tlin / (NW / TX);
    int txi = tlin - tyi * (NW / TX);
    int bx0 = txi * TX, by0 = tyi * TY;
    int tid = threadIdx.x;
    int lane = tid & 63;
    int wv = tid >> 6;
    int tx = lane;
    int ty0 = wv * 4;

    for (int f = 0; f < 2; ++f) {
        const float* img = (f == 0 ? s1m : w2m) + (size_t)b * HW;
        if (f) __syncthreads();
        for (int i = tid; i < (TY + 4) * (TX + 4); i += 256) {
            int ly = i / (TX + 4), lx = i - ly * (TX + 4);
            int gy = by0 + ly - 2, gx = bx0 + lx - 2;
            tile[i] = (gy >= 0 && gy < NH && gx >= 0 && gx < NW)
                    ? img[gy * NW + gx] : -1e30f;
        }
        __syncthreads();

        unsigned long long keys[4];
        int slot[4];
        int wtot = 0;
#pragma unroll
        for (int r = 0; r < 4; ++r) {
            int ty = ty0 + r;
            float c = tile[(ty + 2) * (TX + 4) + tx + 2];
            bool pk = false;
            if (c > NMS_T) {
                float m = -1e30f;
#pragma unroll
                for (int dy = 0; dy < 5; ++dy)
#pragma unroll
                    for (int dx = 0; dx < 5; ++dx)
                        m = fmaxf(m, tile[(ty + dy) * (TX + 4) + tx + dx]);
                pk = (m <= c);
            }
            unsigned long long bal = __ballot(pk);
            if (pk) {
                int rem = (by0 + ty) * NW + bx0 + tx;
                keys[r] = ((unsigned long long)__float_as_uint(c) << 32) |
                          (unsigned long long)(0xFFFFFFFFu - (unsigned int)rem);
                slot[r] = wtot + (int)__popcll(bal & ((1ull << lane) - 1ull));
            } else {
                slot[r] = -1;
            }
            wtot += (int)__popcll(bal);
        }
        if (lane == 0) wsum[wv] = wtot;
        __syncthreads();
        if (tid == 0) {
            int total = wsum[0] + wsum[1] + wsum[2] + wsum[3];
            base_sh = atomicAdd(&cntp[(f * NB + b) * 16], total);
        }
        __syncthreads();
        int wbase = base_sh;
        for (int i2 = 0; i2 < wv; ++i2) wbase += wsum[i2];
        unsigned long long* dst = cand + (size_t)(f * NB + b) * CAP;
#pragma unroll
        for (int r = 0; r < 4; ++r)
            if (slot[r] >= 0) {
                int p = wbase + slot[r];
                if (p < CAP) dst[p] = keys[r];
            }
    }
}

// ---- bucket-select top-1024 (few barriers) + (field0: ordered kp | field1: stamp)
// bucket = (valbits>>12) - 0x3E999 : monotonic in value, values in (0.3, 1.0]
struct GaussK { float g[25]; };

__global__ __launch_bounds__(1024) void select_kernel(
    const unsigned long long* __restrict__ cand, const int* __restrict__ cntp,
    float* __restrict__ out, float* __restrict__ gt, GaussK gk)
{
    __shared__ unsigned int hist[4096];        // bucket counts C
    __shared__ unsigned int cnt2[4096];        // arrival counters
    __shared__ unsigned int scn[4097];         // suffix sums S
    __shared__ unsigned long long sel[TOPK];
    __shared__ unsigned long long tbuf[1024];  // bucket-T keys
    __shared__ unsigned int ws16[16];
    __shared__ int sh_T, sh_need;
    __shared__ unsigned int tcnt;
    __shared__ unsigned long long sh_kstar;

    int blk = blockIdx.x;     // 0..63
    int field = blk >> 5;
    int b = blk & 31;
    int tid = threadIdx.x;
    int n = cntp[(field * NB + b) * 16];
    if (n > CAP) n = CAP;
    int selK = n < TOPK ? n : TOPK;
    const unsigned long long* src = cand + (size_t)(field * NB + b) * CAP;

    for (int i = tid; i < 4096; i += 1024) { hist[i] = 0; cnt2[i] = 0; }
    for (int i = tid; i < TOPK; i += 1024) sel[i] = 0ULL;
    if (tid == 0) { tcnt = 0; scn[4096] = 0; sh_T = 4095; sh_need = 0; }
    __syncthreads();                                            // B1

    // histogram by value bucket
    for (int i = tid; i < n; i += 1024) {
        unsigned int vb = (unsigned int)(src[i] >> 32);
        atomicAdd(&hist[(vb >> 12) - 0x3E999u], 1u);
    }
    __syncthreads();                                            // B2

    // hierarchical suffix scan: thread owns bins 4t..4t+3
    int base4 = tid * 4;
    unsigned int c0 = hist[base4], c1 = hist[base4 + 1];
    unsigned int c2 = hist[base4 + 2], c3 = hist[base4 + 3];
    unsigned int own = c0 + c1 + c2 + c3;
    unsigned int sfx = own;
    int lane = tid & 63, wv = tid >> 6;
    for (int off = 1; off < 64; off <<= 1) {
        unsigned int v = __shfl_down(sfx, off, 64);
        if (lane + off < 64) sfx += v;   // inclusive suffix within wave
    }
    if (lane == 0) ws16[wv] = sfx;       // wave total
    __syncthreads();                                            // B3
    unsigned int wo = 0;
    for (int w = wv + 1; w < 16; ++w) wo += ws16[w];
    unsigned int excl = wo + (sfx - own); // sum over threads strictly after
    unsigned int s3 = excl + c3;
    unsigned int s2v = s3 + c2;
    unsigned int s1v = s2v + c1;
    unsigned int s0 = s1v + c0;
    scn[base4] = s0; scn[base4 + 1] = s1v;
    scn[base4 + 2] = s2v; scn[base4 + 3] = s3;
    __syncthreads();                                            // B4

    // threshold bucket T: S[T] >= selK > S[T+1]
    if (selK > 0) {
#pragma unroll
        for (int r = 0; r < 4; ++r) {
            int bin = base4 + r;
            unsigned int S = scn[bin], Sn = scn[bin + 1];
            if (S >= (unsigned int)selK && Sn < (unsigned int)selK) {
                sh_T = bin; sh_need = selK - (int)Sn;
            }
        }
    }
    __syncthreads();                                            // B5
    int T = sh_T, need = sh_need;

    // collect bucket-T keys
    for (int i = tid; i < n; i += 1024) {
        unsigned long long k = src[i];
        unsigned int vb = (unsigned int)(k >> 32);
        if ((int)((vb >> 12) - 0x3E999u) == T) {
            unsigned int p = atomicAdd(&tcnt, 1u);
            if (p < 1024) tbuf[p] = k;
        }
    }
    __syncthreads();                                            // B6
    if (tid == 0) {
        int m = tcnt > 1024u ? 1024 : (int)tcnt;  // expected ~5
        for (int i = 1; i < m; ++i) {             // insertion sort desc
            unsigned long long key = tbuf[i]; int j = i - 1;
            while (j >= 0 && tbuf[j] < key) { tbuf[j + 1] = tbuf[j]; --j; }
            tbuf[j + 1] = key;
        }
        sh_kstar = (need > 0) ? tbuf[need - 1] : ~0ULL;
    }
    __syncthreads();                                            // B7
    unsigned long long kstar = sh_kstar;

    // gather + direct placement: pos = S[bucket+1] + arrival-within-bucket
    for (int i = tid; i < n; i += 1024) {
        unsigned long long k = src[i];
        if (k >= kstar) {
            unsigned int vb = (unsigned int)(k >> 32);
            int bin = (int)((vb >> 12) - 0x3E999u);
            unsigned int pos = scn[bin + 1] + atomicAdd(&cnt2[bin], 1u);
            sel[pos] = k;
        }
    }
    __syncthreads();                                            // B8

    // fix-up: sort each bucket's run (disjoint ranges, expected len ~1-8)
    for (int bin = T + tid; bin < 4096; bin += 1024) {
        int len = (bin == T) ? need : (int)hist[bin];
        if (len >= 2) {
            unsigned int rb = scn[bin + 1];
            for (int i = 1; i < len; ++i) {
                unsigned long long key = sel[rb + i]; int j = i - 1;
                while (j >= 0 && sel[rb + j] < key) { sel[rb + j + 1] = sel[rb + j]; --j; }
                sel[rb + j + 1] = key;
            }
        }
    }
    __syncthreads();                                            // B9

    if (field == 0) {
        if (tid < TOPK) {
            unsigned long long key = sel[tid];
            unsigned int vb = (unsigned int)(key >> 32);
            int idx = (int)(0xFFFFFFFFu - (unsigned int)key);
            if (vb == 0) idx = tid; // padding (never hit: n >> 1024)
            int y = idx / NW, x = idx - y * NW;
            out[1 + ((size_t)b * TOPK + tid) * 2 + 0] = (float)y;
            out[1 + ((size_t)b * TOPK + tid) * 2 + 1] = (float)x;
        }
    } else {
        if (tid < TOPK) {
            unsigned long long key = sel[tid];
            unsigned int vb = (unsigned int)(key >> 32);
            if (vb != 0) {
                float v = __uint_as_float(vb);
                int idx = (int)(0xFFFFFFFFu - (unsigned int)key);
                int y = idx / NW, x = idx - y * NW;
                float* img = gt + (size_t)b * HW;
#pragma unroll
                for (int dy = -2; dy <= 2; ++dy) {
                    int yy = y + dy;
                    if (yy < 0 || yy >= NH) continue;
#pragma unroll
                    for (int dx = -2; dx <= 2; ++dx) {
                        int xx = x + dx;
                        if (xx < 0 || xx >= NW) continue;
                        atomicAdd(&img[yy * NW + xx], v * gk.g[(dy + 2) * 5 + (dx + 2)]);
                    }
                }
            }
        }
    }
}

// ---------------------------------------------------------------- loss
__global__ __launch_bounds__(256) void loss_kernel(
    const float* __restrict__ a, const float* __restrict__ g,
    double* __restrict__ buck)
{
    double acc = 0.0;
    int stride = gridDim.x * 256;
    for (int i = blockIdx.x * 256 + threadIdx.x; i < BHW; i += stride) {
        float d = a[i] - g[i];
        float sq = d * d;
        acc += (double)sq;
    }
    for (int off = 32; off; off >>= 1) acc += __shfl_down(acc, off, 64);
    __shared__ double wsum[4];
    int lane = threadIdx.x & 63, wid = threadIdx.x >> 6;
    if (lane == 0) wsum[wid] = acc;
    __syncthreads();
    if (threadIdx.x == 0) {
        double t = wsum[0] + wsum[1] + wsum[2] + wsum[3];
        atomicAdd(&buck[(blockIdx.x & 63) * 8], t);
    }
}

__global__ __launch_bounds__(256) void final_kernel(
    const double* __restrict__ lbp, const unsigned int* __restrict__ nbp,
    float* __restrict__ out)
{
    __shared__ double ds[4];
    __shared__ unsigned int us[4];
    int tid = threadIdx.x, lane = tid & 63, wv = tid >> 6;
    unsigned int nv = nbp[tid * 16];
    double lv = (tid < 64) ? lbp[tid * 8] : 0.0;
    for (int off = 32; off; off >>= 1) {
        nv += __shfl_down(nv, off, 64);
        lv += __shfl_down(lv, off, 64);
    }
    if (lane == 0) { us[wv] = nv; ds[wv] = lv; }
    __syncthreads();
    if (tid == 0) {
        double t = ds[0] + ds[1] + ds[2] + ds[3];
        unsigned long long nn = (unsigned long long)us[0] + us[1] + us[2] + us[3];
        out[0] = (float)(t / (double)nn);
    }
}

// ---------------------------------------------------------------- launch
extern "C" void kernel_launch(void* const* d_in, const int* in_sizes, int n_in,
                              void* d_out, int out_size, void* d_ws, size_t ws_size,
                              hipStream_t stream)
{
    const float* s1 = (const float*)d_in[0];
    const float* s2 = (const float*)d_in[1];
    const float* homo = (const float*)d_in[2];
    float* out = (float*)d_out;

    char* ws = (char*)d_ws;
    const size_t FB = (size_t)BHW * 4;               // 39,321,600 B
    float* s1m = (float*)ws;                         // [0, FB)
    float* w2 = (float*)(ws + FB);                   // [FB, 2FB) ; reused as gt
    size_t off = 2 * FB;
    unsigned long long* cand = (unsigned long long*)(ws + off);  // 8 MiB
    off += (size_t)2 * NB * CAP * 8;
    int* cntp = (int*)(ws + off);                         // 64 * 64B  = 4 KiB
    unsigned int* nbp = (unsigned int*)(ws + off + 4096); // 256 * 64B = 16 KiB
    double* lbp = (double*)(ws + off + 20480);            // 64 * 64B  = 4 KiB

    float* mask_out = out + 1 + (size_t)NB * TOPK * 2;

    GaussK gk;
    {
        double gg[5];
        for (int i = 0; i < 5; ++i) {
            double ax = (double)i - 2.0;
            gg[i] = ::exp(-(ax * ax) / 8.0);
        }
        double tot = 0.0;
        for (int i = 0; i < 5; ++i)
            for (int j = 0; j < 5; ++j) tot += gg[i] * gg[j];
        for (int i = 0; i < 5; ++i)
            for (int j = 0; j < 5; ++j)
                gk.g[i * 5 + j] = (float)(gg[i] * gg[j] / tot);
    }

    hipMemsetAsync(cntp, 0, 24576, stream); // cntp + nbp + lbp
    prep_kernel<<<dim3(300, NB), 256, 0, stream>>>(s1, s2, homo, s1m, w2, mask_out, nbp);
    nms_kernel<<<dim3(300, NB), 256, 0, stream>>>(s1m, w2, cand, cntp);
    hipMemsetAsync(w2, 0, FB, stream); // w2m no longer needed -> becomes gt map
    select_kernel<<<64, 1024, 0, stream>>>(cand, cntp, out, w2, gk);
    loss_kernel<<<2048, 256, 0, stream>>>(s1m, w2, lbp);
    final_kernel<<<1, 256, 0, stream>>>(lbp, nbp, out);
}